// Round 1
// baseline (390.348 us; speedup 1.0000x reference)
//
#include <hip/hip_runtime.h>
#include <cstdint>
#include <cstddef>

// Problem constants (from reference: B,T,N = 512,1024,48)
constexpr int Bb = 512;
constexpr int Tt = 1024;
constexpr int Nn = 48;

typedef float f2 __attribute__((ext_vector_type(2)));
typedef float f4 __attribute__((ext_vector_type(4)));

// One wave (64 lanes) per batch element. Lane j < 48 owns state j.
// Forward recursion in exp-domain: new_a[j] = M + ln( sum_i exp(a[i]-M) * et[i][j] ) + pot[t][j]
// with et[i][j] = exp(trans[i][j]) resident in 48 VGPRs per lane (column j),
// and e[i] = exp(a[i]-M) broadcast through LDS (uniform b128 reads).
__launch_bounds__(64)
__global__ void crf_nll_kernel(const float* __restrict__ pot,
                               const int*   __restrict__ ytrue,
                               const int*   __restrict__ lengths,
                               const float* __restrict__ trans,
                               float*       __restrict__ out)
{
    __shared__ __align__(16) float e_lds[64];
    __shared__ float trans_lds[Nn * Nn];
    __shared__ int   y_lds[Tt];

    const int b      = blockIdx.x;
    const int lane   = threadIdx.x;
    const int lane_c = (lane < Nn) ? lane : (Nn - 1);   // clamped lane: keeps loads in-bounds, no divergence
    const int len    = lengths[b];                      // in [1, T]

    // Stage transitions (9 KB) and this sequence's tags (4 KB) into LDS once.
    for (int i = lane; i < Nn * Nn; i += 64) trans_lds[i] = trans[i];
    const int* yrow = ytrue + (size_t)b * Tt;
    for (int i = lane; i < Tt; i += 64) y_lds[i] = yrow[i];
    __syncthreads();

    // et column j in registers: et2[k] = { exp(trans[2k][j]), exp(trans[2k+1][j]) }
    f2 et2[Nn / 2];
#pragma unroll
    for (int k = 0; k < Nn / 2; ++k) {
        et2[k].x = __expf(trans_lds[(2 * k)     * Nn + lane_c]);
        et2[k].y = __expf(trans_lds[(2 * k + 1) * Nn + lane_c]);
    }

    const float* prow = pot + (size_t)b * Tt * Nn;

    // t = 0 init
    const float pot0 = prow[lane_c];
    float alpha  = (lane < Nn) ? pot0 : -1e30f;
    const int y0 = y_lds[0];
    float unary  = (lane == y0) ? pot0 : 0.0f;
    float binary = 0.0f;
    int   y_prev = y0;

    // Prefetch ring: rows t=1..8 (always in-bounds, T=1024)
    float p0 = prow[1 * Nn + lane_c];
    float p1 = prow[2 * Nn + lane_c];
    float p2 = prow[3 * Nn + lane_c];
    float p3 = prow[4 * Nn + lane_c];
    float p4 = prow[5 * Nn + lane_c];
    float p5 = prow[6 * Nn + lane_c];
    float p6 = prow[7 * Nn + lane_c];
    float p7 = prow[8 * Nn + lane_c];

    auto step = [&](float pot_cur, int tcur) {
        // Cheap shift: alpha spread across states is bounded (~20), so lane0's
        // alpha keeps exp() comfortably in fp32 range. 1 readlane instead of a
        // 6-op wave max-reduce.
        const float M = __shfl(alpha, 0);
        const float e = __expf(alpha - M);          // lanes >= 48: exp(-1e30-M) = 0
        e_lds[lane] = e;
        // (compiler inserts lgkmcnt wait; DS ops are in-order per wave)
        f2 a0 = {0.0f, 0.0f};
        f2 a1 = {0.0f, 0.0f};
#pragma unroll
        for (int m = 0; m < Nn / 4; ++m) {
            const f4 ev = *(const f4*)(e_lds + 4 * m);   // uniform broadcast read
            f2 lo; lo.x = ev.x; lo.y = ev.y;
            f2 hi; hi.x = ev.z; hi.y = ev.w;
            a0 += lo * et2[2 * m];
            a1 += hi * et2[2 * m + 1];
        }
        const float s = (a0.x + a1.x) + (a0.y + a1.y);   // s >= et[0][j] > 0, log is safe

        const int   y_cur = y_lds[tcur];
        const float tr    = trans_lds[y_prev * Nn + lane_c];

        const float na = M + __logf(s) + pot_cur;
        alpha = (lane < Nn) ? na : -1e30f;

        const float sel = (lane == y_cur) ? 1.0f : 0.0f; // y_cur < 48, so lanes >= 48 never add
        unary  = fmaf(sel, pot_cur, unary);
        binary = fmaf(sel, tr, binary);
        y_prev = y_cur;
    };

    int t = 1;
    // Main loop: 8-step unroll, each slot consumes its row and prefetches row t+8.
#define SLOT(P)                                                   \
    do {                                                          \
        step(P, t);                                               \
        int tn = t + 8; if (tn > Tt - 1) tn = Tt - 1;             \
        P = prow[(size_t)tn * Nn + lane_c];                       \
        ++t;                                                      \
    } while (0)

    while (t + 8 <= len) {
        SLOT(p0); SLOT(p1); SLOT(p2); SLOT(p3);
        SLOT(p4); SLOT(p5); SLOT(p6); SLOT(p7);
    }
#undef SLOT
    // Tail (< 8 steps): direct loads, latency acceptable.
    while (t < len) {
        const float pc = prow[(size_t)t * Nn + lane_c];
        step(pc, t);
        ++t;
    }

    // log_norm = logsumexp over states of final alpha (lanes >= 48 hold -1e30 -> exp 0)
    float m = alpha;
#pragma unroll
    for (int off = 32; off > 0; off >>= 1) m = fmaxf(m, __shfl_xor(m, off));
    float se = __expf(alpha - m);
#pragma unroll
    for (int off = 32; off > 0; off >>= 1) se += __shfl_xor(se, off);
    const float lse = m + __logf(se);

    float sc = unary + binary;
#pragma unroll
    for (int off = 32; off > 0; off >>= 1) sc += __shfl_xor(sc, off);

    if (lane == 0) out[b] = lse - sc;   // NLL = log_norm - seq_score
}

extern "C" void kernel_launch(void* const* d_in, const int* in_sizes, int n_in,
                              void* d_out, int out_size, void* d_ws, size_t ws_size,
                              hipStream_t stream)
{
    const float* pot    = (const float*)d_in[0];
    const int*   ytrue  = (const int*)  d_in[1];
    const int*   lens   = (const int*)  d_in[2];
    const float* trans  = (const float*)d_in[3];
    float*       out    = (float*)d_out;

    crf_nll_kernel<<<dim3(Bb), dim3(64), 0, stream>>>(pot, ytrue, lens, trans, out);
}

// Round 2
// 310.184 us; speedup vs baseline: 1.2584x; 1.2584x over previous
//
#include <hip/hip_runtime.h>
#include <cstdint>
#include <cstddef>

// Problem constants (from reference: B,T,N = 512,1024,48)
constexpr int Bb = 512;
constexpr int Tt = 1024;
constexpr int Nn = 48;

typedef float f2 __attribute__((ext_vector_type(2)));
typedef float f4 __attribute__((ext_vector_type(4)));

__device__ __forceinline__ float readlane0(float v) {
    return __int_as_float(__builtin_amdgcn_readlane(__float_as_int(v), 0));
}

// One wave (= one block) per batch element. Lane j < 48 owns state j.
//
// Scaled forward algorithm (exp-domain, lazy normalization):
//   a_{t+1}[j] = (sum_i a_t[i] * ET[i][j]) * exp(pot[t+1][j]) * r_t
//   r_t = 1/a_t[0],  logZ += log(a_t[0])
// log_norm = log(sum_j a_final[j]) + c0 + sum_t log(c_t)
//
// Critical path per step is ONLY: ds_write(a) -> 12x ds_read_b128 (uniform
// broadcast, conflict-free) -> 24 v_pk_fma_f32 (8 accumulators, depth 6)
// -> h-add -> 1 mul. exp/log/rcp/readlane all run in the LDS-latency shadow.
__launch_bounds__(64)
__global__ void crf_nll_kernel(const float* __restrict__ pot,
                               const int*   __restrict__ ytrue,
                               const int*   __restrict__ lengths,
                               const float* __restrict__ trans,
                               float*       __restrict__ out)
{
    __shared__ __align__(16) float a_lds[64];
    __shared__ float trans_lds[Nn * Nn];

    const int b      = blockIdx.x;
    const int lane   = threadIdx.x;
    const int lane_c = (lane < Nn) ? lane : (Nn - 1);   // clamped: in-bounds, no divergence
    const int len    = lengths[b];                      // in [1, T]

    for (int i = lane; i < Nn * Nn; i += 64) trans_lds[i] = trans[i];
    __syncthreads();   // single wave, but keeps LDS visibility explicit

    const int*   yrow = ytrue + (size_t)b * Tt;
    const float* prow = pot + (size_t)b * Tt * Nn;

    // ---- Gold-path score: fully parallel pre-pass (off the sequential chain).
    // Lane handles t = lane, lane+64, ... ; all loads unconditional (in-bounds),
    // adds predicated. 16 independent iterations -> load latency pipelined.
    float gold = 0.0f;
#pragma unroll
    for (int k = 0; k < Tt / 64; ++k) {
        const int   t    = lane + 64 * k;
        const int   yt   = yrow[t];
        const int   ytm1 = yrow[(t > 0) ? (t - 1) : 0];
        const float u    = prow[(size_t)t * Nn + yt];
        const float tr   = trans_lds[ytm1 * Nn + yt];
        const float m1   = (t < len) ? 1.0f : 0.0f;
        const float m2   = (t >= 1 && t < len) ? 1.0f : 0.0f;
        gold = fmaf(m1, u, gold);
        gold = fmaf(m2, tr, gold);
    }

    // et column j resident in 48 VGPRs/lane: et2[k] = {exp(T[2k][j]), exp(T[2k+1][j])}
    f2 et2[Nn / 2];
#pragma unroll
    for (int k = 0; k < Nn / 2; ++k) {
        et2[k].x = __expf(trans_lds[(2 * k)     * Nn + lane_c]);
        et2[k].y = __expf(trans_lds[(2 * k + 1) * Nn + lane_c]);
    }

    // ---- t = 0 init: a_0 = exp(pot0 - c0), logZ starts at c0.
    const float pot0 = prow[lane_c];
    const float c0   = readlane0(pot0);
    float a    = (lane < Nn) ? __expf(pot0 - c0) : 0.0f;
    float logz = c0;

    // Prefetch ring: rows t=1..8 (always in-bounds, T=1024)
    float p0 = prow[1 * Nn + lane_c];
    float p1 = prow[2 * Nn + lane_c];
    float p2 = prow[3 * Nn + lane_c];
    float p3 = prow[4 * Nn + lane_c];
    float p4 = prow[5 * Nn + lane_c];
    float p5 = prow[6 * Nn + lane_c];
    float p6 = prow[7 * Nn + lane_c];
    float p7 = prow[8 * Nn + lane_c];

    auto step = [&](float p) {
        // Broadcast a through LDS (write then 12 uniform b128 reads; DS pipe
        // is in-order per wave, no barrier needed — block is one wave).
        a_lds[lane] = a;
        // Shadow work (results needed only at the very end of the dot):
        const float c = readlane0(a);                        // c = a_t[0] > 0
        const float f = __expf(p) * __builtin_amdgcn_rcpf(c);
        logz += __logf(c);

        f2 a0 = {0.0f, 0.0f}, a1 = {0.0f, 0.0f};
        f2 a2 = {0.0f, 0.0f}, a3 = {0.0f, 0.0f};
#pragma unroll
        for (int m = 0; m < 6; ++m) {
            const f4 v0 = *(const f4*)(a_lds + 8 * m);
            const f4 v1 = *(const f4*)(a_lds + 8 * m + 4);
            f2 lo0; lo0.x = v0.x; lo0.y = v0.y;
            f2 hi0; hi0.x = v0.z; hi0.y = v0.w;
            f2 lo1; lo1.x = v1.x; lo1.y = v1.y;
            f2 hi1; hi1.x = v1.z; hi1.y = v1.w;
            a0 += lo0 * et2[4 * m];
            a1 += hi0 * et2[4 * m + 1];
            a2 += lo1 * et2[4 * m + 2];
            a3 += hi1 * et2[4 * m + 3];
        }
        const f2 s2 = (a0 + a1) + (a2 + a3);
        const float s = s2.x + s2.y;     // s > 0 (products/sums of positives)
        a = s * f;                       // lanes >= 48 hold junk; masked at the end
    };

    int t = 1;
#define SLOT(P)                                                   \
    do {                                                          \
        step(P);                                                  \
        int tn = t + 8; if (tn > Tt - 1) tn = Tt - 1;             \
        P = prow[(size_t)tn * Nn + lane_c];                       \
        ++t;                                                      \
    } while (0)

    while (t + 8 <= len) {
        SLOT(p0); SLOT(p1); SLOT(p2); SLOT(p3);
        SLOT(p4); SLOT(p5); SLOT(p6); SLOT(p7);
    }
#undef SLOT
    while (t < len) {
        const float pc = prow[(size_t)t * Nn + lane_c];
        step(pc);
        ++t;
    }

    // log_norm = log(sum_j a[j]) + logz   (mask junk lanes >= 48)
    float se = (lane < Nn) ? a : 0.0f;
#pragma unroll
    for (int off = 32; off > 0; off >>= 1) se += __shfl_xor(se, off);
    const float log_norm = __logf(se) + logz;

    float g = gold;
#pragma unroll
    for (int off = 32; off > 0; off >>= 1) g += __shfl_xor(g, off);

    if (lane == 0) out[b] = log_norm - g;   // NLL = log_norm - seq_score
}

extern "C" void kernel_launch(void* const* d_in, const int* in_sizes, int n_in,
                              void* d_out, int out_size, void* d_ws, size_t ws_size,
                              hipStream_t stream)
{
    const float* pot    = (const float*)d_in[0];
    const int*   ytrue  = (const int*)  d_in[1];
    const int*   lens   = (const int*)  d_in[2];
    const float* trans  = (const float*)d_in[3];
    float*       out    = (float*)d_out;

    crf_nll_kernel<<<dim3(Bb), dim3(64), 0, stream>>>(pot, ytrue, lens, trans, out);
}